// Round 14
// baseline (288.123 us; speedup 1.0000x reference)
//
#include <hip/hip_runtime.h>
#include <hip/hip_fp16.h>

#define NN 50000      // nodes
#define NE 800000     // edges
#define DIM 128       // feature dim (D == H)
#define NG 64         // graphs
#define NOUT 10       // output dim

#define NBKT 391      // coarse buckets: ceil(NN/128), dst>>7
#define HBLK 256      // histogram/scatter blocks
#define CHUNK ((NE + HBLK - 1) / HBLK)   // 3125 edges per block

#define WPAD 136                 // W LDS/global row stride in shorts (16B-aligned rows)
#define PSTR (DIM * WPAD)        // one W plane = 17408 shorts (34.8 KB)

typedef __attribute__((ext_vector_type(8))) short short8;
typedef __attribute__((ext_vector_type(8))) _Float16 half8;
typedef __attribute__((ext_vector_type(4))) float float4v;

union S8H8 { short8 s; half8 h; };
union SH { short s; _Float16 h; };

// ---------------------------------------------------------------- fused prep:
// blocks [0,48)      : W f32 [k][n] -> fp16 RNE, transposed [n][k],
//                      row-rotated (phys_k = (k + 8*(n>>3)) & 127), stride WPAD
// blocks [48,304)    : per-block dst-bucket histogram
// block  304         : graph boundaries (batch sorted)
#define PREP_WB 48
#define PREP_HB (PREP_WB + HBLK)   // 304
#define PREP_NB (PREP_HB + 1)      // 305
__global__ __launch_bounds__(256) void prep_kernel(const float* __restrict__ W0,
                                                   const float* __restrict__ W1,
                                                   const float* __restrict__ W2,
                                                   short* __restrict__ wsp,
                                                   const int* __restrict__ ei,
                                                   int* __restrict__ blkhist,
                                                   const int* __restrict__ batch,
                                                   int* __restrict__ first) {
    __shared__ int h[NBKT];
    int bx = blockIdx.x;
    if (bx < PREP_WB) {
        int w = bx >> 4;
        int sub = bx & 15;
        const float* W = (w == 0) ? W0 : (w == 1) ? W1 : W2;
        short* Wp = wsp + w * PSTR;
        #pragma unroll
        for (int t = 0; t < 4; ++t) {
            int idx = sub * 1024 + t * 256 + threadIdx.x;
            int k = idx >> 7, n = idx & 127;
            int phys = n * WPAD + ((k + 8 * (n >> 3)) & 127);
            SH c;
            c.h = (_Float16)W[idx];  // RNE
            Wp[phys] = c.s;
        }
    } else if (bx < PREP_HB) {
        int b = bx - PREP_WB;
        for (int i = threadIdx.x; i < NBKT; i += 256) h[i] = 0;
        __syncthreads();
        int lo = b * CHUNK, hi = min(lo + CHUNK, NE);
        for (int e = lo + threadIdx.x; e < hi; e += 256)
            atomicAdd(&h[ei[NE + e] >> 7], 1);  // LDS atomic
        __syncthreads();
        for (int i = threadIdx.x; i < NBKT; i += 256)
            blkhist[b * NBKT + i] = h[i];
    } else {
        int g = threadIdx.x;
        if (g <= NG) {
            int lo = 0, hi = NN;
            while (lo < hi) {
                int mid = (lo + hi) >> 1;
                if (batch[mid] < g) lo = mid + 1; else hi = mid;
            }
            first[g] = lo;  // lower_bound(batch, g)
        }
    }
}

// ---------------------------------------------------------------- scan_all: per-bucket column scan + totals
__global__ __launch_bounds__(256) void scan_all(int* __restrict__ blkhist,
                                                int* __restrict__ bintot) {
    __shared__ int s[256];
    int bin = blockIdx.x;
    int t = threadIdx.x;
    int v = blkhist[t * NBKT + bin];
    s[t] = v;
    __syncthreads();
    #pragma unroll
    for (int off = 1; off < 256; off <<= 1) {
        int tv = (t >= off) ? s[t - off] : 0;
        __syncthreads();
        s[t] += tv;
        __syncthreads();
    }
    blkhist[t * NBKT + bin] = s[t] - v;  // exclusive (bucket-local)
    if (t == 255) bintot[bin] = s[255];
}

// ---------------------------------------------------------------- scan bucket totals -> bucket_base
__global__ __launch_bounds__(512) void base_scan_kernel(const int* __restrict__ bintot,
                                                        int* __restrict__ bucket_base) {
    __shared__ int s[512];
    int t = threadIdx.x;
    int v = (t < NBKT) ? bintot[t] : 0;
    s[t] = v;
    __syncthreads();
    #pragma unroll
    for (int off = 1; off < 512; off <<= 1) {
        int tv = (t >= off) ? s[t - off] : 0;
        __syncthreads();
        s[t] += tv;
        __syncthreads();
    }
    if (t <= NBKT) bucket_base[t] = s[t] - v;  // exclusive; t==NBKT -> NE
}

// ---------------------------------------------------------------- scatter edges into buckets (packed)
__global__ __launch_bounds__(256) void bucket_scatter(const int* __restrict__ ei,
                                                      const int* __restrict__ blkhist,
                                                      const int* __restrict__ bucket_base,
                                                      unsigned* __restrict__ ebuf) {
    __shared__ int cur[NBKT];
    int b = blockIdx.x;
    for (int i = threadIdx.x; i < NBKT; i += 256)
        cur[i] = blkhist[b * NBKT + i] + bucket_base[i];
    __syncthreads();
    int lo = b * CHUNK, hi = min(lo + CHUNK, NE);
    for (int e = lo + threadIdx.x; e < hi; e += 256) {
        int s = ei[e];
        int d = ei[NE + e];
        int pos = atomicAdd(&cur[d >> 7], 1);  // LDS atomic; block owns disjoint ranges
        ebuf[pos] = ((unsigned)(d & 127) << 16) | (unsigned)s;  // src < 2^16
    }
}

// ---------------------------------------------------------------- per-bucket CSR build
__global__ __launch_bounds__(128) void build_csr(const unsigned* __restrict__ ebuf,
                                                 const int* __restrict__ bucket_base,
                                                 int* __restrict__ rowoff,
                                                 int* __restrict__ csr_src,
                                                 float* __restrict__ dinv) {
    __shared__ int deg[128];
    __shared__ int loff[128];
    int g = blockIdx.x;
    int lo = bucket_base[g], hi = bucket_base[g + 1];
    int t = threadIdx.x;
    deg[t] = 0;
    __syncthreads();
    for (int p = lo + t; p < hi; p += 128)
        atomicAdd(&deg[ebuf[p] >> 16], 1);
    __syncthreads();
    int v = deg[t];
    loff[t] = v;
    __syncthreads();
    #pragma unroll
    for (int off = 1; off < 128; off <<= 1) {
        int tv = (t >= off) ? loff[t - off] : 0;
        __syncthreads();
        loff[t] += tv;
        __syncthreads();
    }
    int excl = loff[t] - v;
    int node = g * 128 + t;
    if (node < NN) {
        rowoff[node] = lo + excl;
        dinv[node] = 1.0f / sqrtf((float)v + 1.0f);
    }
    if (node == 0) rowoff[NN] = NE;
    deg[t] = lo + excl;  // reuse as cursor
    __syncthreads();
    for (int p = lo + t; p < hi; p += 128) {
        unsigned pk = ebuf[p];
        int pos = atomicAdd(&deg[pk >> 16], 1);
        csr_src[pos] = (int)(pk & 0xFFFFu);
    }
}

// ---------------------------------------------------------------- GEMM: Y(fp16) = A @ W, 1-term fp16 MFMA
// W single fp16 plane in LDS (34.8 KB -> 4 blocks/CU). B-tile n0 covers
// W-cols {lm*8+n0}; rotated layout keeps LDS banks at 2 lanes/bank (free).
// Epilogue: 8 RNE halves packed into one 16 B store per (t,rg).
template <bool AF32>
__global__ __launch_bounds__(256) void gemm_mfma(const float* __restrict__ Xf,
                                                 const __half* __restrict__ Xh,
                                                 const short* __restrict__ Wsp,
                                                 __half* __restrict__ Y, int nrows) {
    __shared__ short Wp[PSTR];  // 34.8 KB
    int tid = threadIdx.x;
    {
        const short8* g = (const short8*)Wsp;  // 2176 short8
        #pragma unroll
        for (int i = 0; i < 9; ++i) {
            int e = tid + 256 * i;
            if (e < PSTR / 8) *(short8*)&Wp[e * 8] = g[e];
        }
    }
    int wave = tid >> 6;
    int lane = tid & 63;
    int lm = lane & 15;   // A row within tile / B tile-col / D col
    int lq = lane >> 4;   // k-octet selector / D row-quad
    int row_t0 = blockIdx.x * 128 + wave * 32;  // this wave: rows [row_t0, row_t0+32)

    float4v acc[2][8];
    #pragma unroll
    for (int t = 0; t < 2; ++t)
        #pragma unroll
        for (int i = 0; i < 8; ++i) acc[t][i] = (float4v){0.f, 0.f, 0.f, 0.f};

    __syncthreads();
    #pragma unroll
    for (int kk = 0; kk < 4; ++kk) {
        half8 a[2];
        #pragma unroll
        for (int t = 0; t < 2; ++t) {
            int r = min(row_t0 + t * 16 + lm, nrows - 1);
            size_t ao = (size_t)r * DIM + kk * 32 + lq * 8;
            if (AF32) {
                float4 xa = *(const float4*)(Xf + ao);
                float4 xb = *(const float4*)(Xf + ao + 4);
                a[t][0] = (_Float16)xa.x; a[t][1] = (_Float16)xa.y;
                a[t][2] = (_Float16)xa.z; a[t][3] = (_Float16)xa.w;
                a[t][4] = (_Float16)xb.x; a[t][5] = (_Float16)xb.y;
                a[t][6] = (_Float16)xb.z; a[t][7] = (_Float16)xb.w;
            } else {
                S8H8 u;
                u.s = *(const short8*)((const short*)Xh + ao);
                a[t] = u.h;
            }
        }
        int pk = (kk * 32 + lq * 8 + 8 * lm) & 127;  // rotated k offset for row 8lm+n0
        #pragma unroll
        for (int n0 = 0; n0 < 8; ++n0) {
            S8H8 b;
            b.s = *(const short8*)&Wp[(lm * 8 + n0) * WPAD + pk];
            #pragma unroll
            for (int t = 0; t < 2; ++t)
                acc[t][n0] = __builtin_amdgcn_mfma_f32_16x16x32_f16(a[t], b.h, acc[t][n0], 0, 0, 0);
        }
    }
    // D: tile-col lm -> W-col lm*8+n0; lane's 8 n0 are contiguous cols lm*8..+7.
    #pragma unroll
    for (int t = 0; t < 2; ++t)
        #pragma unroll
        for (int rg = 0; rg < 4; ++rg) {
            int row = row_t0 + t * 16 + lq * 4 + rg;
            if (row < nrows) {
                short8 o;
                #pragma unroll
                for (int j = 0; j < 8; ++j) {
                    SH c;
                    c.h = (_Float16)acc[t][j][rg];  // RNE
                    o[j] = c.s;
                }
                *(short8*)((short*)Y + (size_t)row * DIM + lm * 8) = o;
            }
        }
}

// ---------------------------------------------------------------- aggregation: 8 groups x 16 lanes x 16 B
// One node per 128-thread block; a 64-lane wave fetches 4 full 256 B rows
// = 16 L2 lines per instruction. Output fp16 (next GEMM A / pool in).
template <bool RELU>
__global__ __launch_bounds__(128) void agg_kernel(const __half* __restrict__ H,
                                                  __half* __restrict__ O16,
                                                  const int* __restrict__ rowoff,
                                                  const int* __restrict__ csr_src,
                                                  const float* __restrict__ dinv) {
    __shared__ float part[8][DIM];
    int i = blockIdx.x;
    int tid = threadIdx.x;
    int grp = tid >> 4;   // 0..7 edge-group
    int ln = tid & 15;    // lane in group; owns cols ln*8 .. ln*8+8
    int s = rowoff[i], e = rowoff[i + 1];
    const __half* Hc = H + ln * 8;

    float a[8] = {0.f, 0.f, 0.f, 0.f, 0.f, 0.f, 0.f, 0.f};
    int p = s + grp;
    for (; p + 8 < e; p += 16) {
        int u0 = csr_src[p];
        int u1 = csr_src[p + 8];
        float d0 = dinv[u0], d1 = dinv[u1];
        short8 q0 = *(const short8*)(Hc + (size_t)u0 * DIM);
        short8 q1 = *(const short8*)(Hc + (size_t)u1 * DIM);
        #pragma unroll
        for (int k = 0; k < 8; ++k) {
            a[k] = fmaf(d0, __half2float(((const __half*)&q0)[k]), a[k]);
            a[k] = fmaf(d1, __half2float(((const __half*)&q1)[k]), a[k]);
        }
    }
    if (p < e) {
        int u = csr_src[p];
        float d = dinv[u];
        short8 q = *(const short8*)(Hc + (size_t)u * DIM);
        #pragma unroll
        for (int k = 0; k < 8; ++k)
            a[k] = fmaf(d, __half2float(((const __half*)&q)[k]), a[k]);
    }
    #pragma unroll
    for (int k = 0; k < 8; k += 4)
        *(float4*)&part[grp][ln * 8 + k] = make_float4(a[k], a[k + 1], a[k + 2], a[k + 3]);
    __syncthreads();
    // thread tid finalizes column tid
    int col = tid;
    float tot = 0.f;
    #pragma unroll
    for (int g2 = 0; g2 < 8; ++g2) tot += part[g2][col];
    float di = dinv[i];
    tot = fmaf(di, __half2float(H[(size_t)i * DIM + col]), tot);  // self-loop
    float v = di * tot;
    if (RELU) v = fmaxf(v, 0.0f);  // relu fused (reference: relu before next conv)
    O16[(size_t)i * DIM + col] = __float2half(v);
}

// ---------------------------------------------------------------- fused pool + MLP: one block per graph
// 256 threads = 8 row-groups x 32 lanes (ushort4 = 8 B -> 256 B row/group).
union U4 { ushort4 u; __half h[4]; };
__global__ __launch_bounds__(256) void pool_mlp(const __half* __restrict__ H,
                                                const int* __restrict__ first,
                                                const float* __restrict__ M0w,
                                                const float* __restrict__ M0b,
                                                const float* __restrict__ M1w,
                                                const float* __restrict__ M1b,
                                                float* __restrict__ out) {
    __shared__ float part[8][DIM];
    __shared__ float p[DIM];
    __shared__ float t2[DIM];
    int g = blockIdx.x;
    int tid = threadIdx.x;
    int rg = tid >> 5, ln = tid & 31;
    int s = first[g], e = first[g + 1];
    float a0 = 0.f, a1 = 0.f, a2 = 0.f, a3 = 0.f;
    for (int r = s + rg; r < e; r += 8) {
        U4 w;
        w.u = *(const ushort4*)(H + (size_t)r * DIM + ln * 4);
        a0 += __half2float(w.h[0]);
        a1 += __half2float(w.h[1]);
        a2 += __half2float(w.h[2]);
        a3 += __half2float(w.h[3]);
    }
    *(float4*)&part[rg][ln * 4] = make_float4(a0, a1, a2, a3);
    __syncthreads();
    if (tid < DIM) {
        float tot = 0.f;
        #pragma unroll
        for (int g2 = 0; g2 < 8; ++g2) tot += part[g2][tid];
        float cnt = (float)max(e - s, 1);
        p[tid] = tot / cnt;
    }
    __syncthreads();
    if (tid < DIM) {
        float acc = M0b[tid];
        #pragma unroll 8
        for (int k = 0; k < DIM; ++k) acc = fmaf(p[k], M0w[k * DIM + tid], acc);
        t2[tid] = fmaxf(acc, 0.0f);
    }
    __syncthreads();
    if (tid < NOUT) {
        float o = M1b[tid];
        #pragma unroll 8
        for (int k = 0; k < DIM; ++k) o = fmaf(t2[k], M1w[k * NOUT + tid], o);
        out[g * NOUT + tid] = o;
    }
}

// ---------------------------------------------------------------- launcher
extern "C" void kernel_launch(void* const* d_in, const int* in_sizes, int n_in,
                              void* d_out, int out_size, void* d_ws, size_t ws_size,
                              hipStream_t stream) {
    const float* x   = (const float*)d_in[0];
    const float* W0  = (const float*)d_in[1];
    const float* W1  = (const float*)d_in[2];
    const float* W2  = (const float*)d_in[3];
    const float* M0w = (const float*)d_in[4];
    const float* M0b = (const float*)d_in[5];
    const float* M1w = (const float*)d_in[6];
    const float* M1b = (const float*)d_in[7];
    const int* ei    = (const int*)d_in[8];
    const int* batch = (const int*)d_in[9];
    float* out = (float*)d_out;

    char* ws = (char*)d_ws;
    size_t off = 0;
    auto take = [&](size_t bytes) -> void* {
        void* p = ws + off;
        off = (off + bytes + 255) & ~(size_t)255;
        return p;
    };
    __half* hA   = (__half*)take((size_t)NN * DIM * 2);   // fp16 GEMM output (gathered)
    __half* hB   = (__half*)take((size_t)NN * DIM * 2);   // fp16 agg output (GEMM A / pool in)
    unsigned* ebuf = (unsigned*)take((size_t)NE * 4);
    int* csr_src = (int*)take((size_t)NE * 4);
    int* blkhist = (int*)take((size_t)HBLK * NBKT * 4);
    int* bintot  = (int*)take((size_t)NBKT * 4);
    int* bucket_base = (int*)take((size_t)(NBKT + 1) * 4);
    int* rowoff  = (int*)take((size_t)(NN + 1) * 4);
    float* dinv  = (float*)take((size_t)NN * 4);
    int* first   = (int*)take((size_t)(NG + 1) * 4);
    short* wsp   = (short*)take((size_t)3 * PSTR * 2);
    (void)ws_size; (void)in_sizes; (void)n_in; (void)out_size;

    // ---- fused prep (W fp16 + hist + bounds), then CSR build
    prep_kernel<<<PREP_NB, 256, 0, stream>>>(W0, W1, W2, wsp, ei, blkhist, batch, first);
    scan_all<<<NBKT, 256, 0, stream>>>(blkhist, bintot);
    base_scan_kernel<<<1, 512, 0, stream>>>(bintot, bucket_base);
    bucket_scatter<<<HBLK, 256, 0, stream>>>(ei, blkhist, bucket_base, ebuf);
    build_csr<<<NBKT, 128, 0, stream>>>(ebuf, bucket_base, rowoff, csr_src, dinv);

    // ---- 3x (GEMM -> aggregate); everything fp16 between stages
    const int GB = (NN + 127) / 128;  // 391 gemm blocks
    gemm_mfma<true><<<GB, 256, 0, stream>>>(x, nullptr, wsp, hA, NN);
    agg_kernel<true><<<NN, 128, 0, stream>>>(hA, hB, rowoff, csr_src, dinv);
    gemm_mfma<false><<<GB, 256, 0, stream>>>(nullptr, hB, wsp + PSTR, hA, NN);
    agg_kernel<true><<<NN, 128, 0, stream>>>(hA, hB, rowoff, csr_src, dinv);
    gemm_mfma<false><<<GB, 256, 0, stream>>>(nullptr, hB, wsp + 2 * PSTR, hA, NN);
    agg_kernel<false><<<NN, 128, 0, stream>>>(hA, hB, rowoff, csr_src, dinv);

    // ---- fused pool + MLP (one block per graph)
    pool_mlp<<<NG, 256, 0, stream>>>(hB, first, M0w, M0b, M1w, M1b, out);
}

// Round 15
// 272.558 us; speedup vs baseline: 1.0571x; 1.0571x over previous
//
#include <hip/hip_runtime.h>
#include <hip/hip_fp16.h>

#define NN 50000      // nodes
#define NE 800000     // edges
#define DIM 128       // feature dim (D == H)
#define NG 64         // graphs
#define NOUT 10       // output dim

#define NBKT 391      // coarse buckets: ceil(NN/128), dst>>7
#define HBLK 256      // histogram/scatter blocks
#define CHUNK ((NE + HBLK - 1) / HBLK)   // 3125 edges per block
#define PSLICE 8      // pooling slices per graph

#define WPAD 136                 // W LDS/global row stride in shorts (16B-aligned rows)
#define PSTR (DIM * WPAD)        // one W plane = 17408 shorts (34.8 KB)

typedef __attribute__((ext_vector_type(8))) short short8;
typedef __attribute__((ext_vector_type(8))) _Float16 half8;
typedef __attribute__((ext_vector_type(4))) float float4v;

union S8H8 { short8 s; half8 h; };
union SH { short s; _Float16 h; };

// ---------------------------------------------------------------- fused prep:
// blocks [0,48)      : W f32 [k][n] -> fp16 RNE, transposed [n][k],
//                      row-rotated (phys_k = (k + 8*(n>>3)) & 127), stride WPAD
// blocks [48,304)    : per-block dst-bucket histogram
// block  304         : graph boundaries (batch sorted)
#define PREP_WB 48
#define PREP_HB (PREP_WB + HBLK)   // 304
#define PREP_NB (PREP_HB + 1)      // 305
__global__ __launch_bounds__(256) void prep_kernel(const float* __restrict__ W0,
                                                   const float* __restrict__ W1,
                                                   const float* __restrict__ W2,
                                                   short* __restrict__ wsp,
                                                   const int* __restrict__ ei,
                                                   int* __restrict__ blkhist,
                                                   const int* __restrict__ batch,
                                                   int* __restrict__ first) {
    __shared__ int h[NBKT];
    int bx = blockIdx.x;
    if (bx < PREP_WB) {
        int w = bx >> 4;
        int sub = bx & 15;
        const float* W = (w == 0) ? W0 : (w == 1) ? W1 : W2;
        short* Wp = wsp + w * PSTR;
        #pragma unroll
        for (int t = 0; t < 4; ++t) {
            int idx = sub * 1024 + t * 256 + threadIdx.x;
            int k = idx >> 7, n = idx & 127;
            int phys = n * WPAD + ((k + 8 * (n >> 3)) & 127);
            SH c;
            c.h = (_Float16)W[idx];  // RNE
            Wp[phys] = c.s;
        }
    } else if (bx < PREP_HB) {
        int b = bx - PREP_WB;
        for (int i = threadIdx.x; i < NBKT; i += 256) h[i] = 0;
        __syncthreads();
        int lo = b * CHUNK, hi = min(lo + CHUNK, NE);
        for (int e = lo + threadIdx.x; e < hi; e += 256)
            atomicAdd(&h[ei[NE + e] >> 7], 1);  // LDS atomic
        __syncthreads();
        for (int i = threadIdx.x; i < NBKT; i += 256)
            blkhist[b * NBKT + i] = h[i];
    } else {
        int g = threadIdx.x;
        if (g <= NG) {
            int lo = 0, hi = NN;
            while (lo < hi) {
                int mid = (lo + hi) >> 1;
                if (batch[mid] < g) lo = mid + 1; else hi = mid;
            }
            first[g] = lo;  // lower_bound(batch, g)
        }
    }
}

// ---------------------------------------------------------------- scan_all: per-bucket column scan + totals
__global__ __launch_bounds__(256) void scan_all(int* __restrict__ blkhist,
                                                int* __restrict__ bintot) {
    __shared__ int s[256];
    int bin = blockIdx.x;
    int t = threadIdx.x;
    int v = blkhist[t * NBKT + bin];
    s[t] = v;
    __syncthreads();
    #pragma unroll
    for (int off = 1; off < 256; off <<= 1) {
        int tv = (t >= off) ? s[t - off] : 0;
        __syncthreads();
        s[t] += tv;
        __syncthreads();
    }
    blkhist[t * NBKT + bin] = s[t] - v;  // exclusive (bucket-local)
    if (t == 255) bintot[bin] = s[255];
}

// ---------------------------------------------------------------- scan bucket totals -> bucket_base
__global__ __launch_bounds__(512) void base_scan_kernel(const int* __restrict__ bintot,
                                                        int* __restrict__ bucket_base) {
    __shared__ int s[512];
    int t = threadIdx.x;
    int v = (t < NBKT) ? bintot[t] : 0;
    s[t] = v;
    __syncthreads();
    #pragma unroll
    for (int off = 1; off < 512; off <<= 1) {
        int tv = (t >= off) ? s[t - off] : 0;
        __syncthreads();
        s[t] += tv;
        __syncthreads();
    }
    if (t <= NBKT) bucket_base[t] = s[t] - v;  // exclusive; t==NBKT -> NE
}

// ---------------------------------------------------------------- scatter edges into buckets (packed)
__global__ __launch_bounds__(256) void bucket_scatter(const int* __restrict__ ei,
                                                      const int* __restrict__ blkhist,
                                                      const int* __restrict__ bucket_base,
                                                      unsigned* __restrict__ ebuf) {
    __shared__ int cur[NBKT];
    int b = blockIdx.x;
    for (int i = threadIdx.x; i < NBKT; i += 256)
        cur[i] = blkhist[b * NBKT + i] + bucket_base[i];
    __syncthreads();
    int lo = b * CHUNK, hi = min(lo + CHUNK, NE);
    for (int e = lo + threadIdx.x; e < hi; e += 256) {
        int s = ei[e];
        int d = ei[NE + e];
        int pos = atomicAdd(&cur[d >> 7], 1);  // LDS atomic; block owns disjoint ranges
        ebuf[pos] = ((unsigned)(d & 127) << 16) | (unsigned)s;  // src < 2^16
    }
}

// ---------------------------------------------------------------- per-bucket CSR build
__global__ __launch_bounds__(128) void build_csr(const unsigned* __restrict__ ebuf,
                                                 const int* __restrict__ bucket_base,
                                                 int* __restrict__ rowoff,
                                                 int* __restrict__ csr_src,
                                                 float* __restrict__ dinv) {
    __shared__ int deg[128];
    __shared__ int loff[128];
    int g = blockIdx.x;
    int lo = bucket_base[g], hi = bucket_base[g + 1];
    int t = threadIdx.x;
    deg[t] = 0;
    __syncthreads();
    for (int p = lo + t; p < hi; p += 128)
        atomicAdd(&deg[ebuf[p] >> 16], 1);
    __syncthreads();
    int v = deg[t];
    loff[t] = v;
    __syncthreads();
    #pragma unroll
    for (int off = 1; off < 128; off <<= 1) {
        int tv = (t >= off) ? loff[t - off] : 0;
        __syncthreads();
        loff[t] += tv;
        __syncthreads();
    }
    int excl = loff[t] - v;
    int node = g * 128 + t;
    if (node < NN) {
        rowoff[node] = lo + excl;
        dinv[node] = 1.0f / sqrtf((float)v + 1.0f);
    }
    if (node == 0) rowoff[NN] = NE;
    deg[t] = lo + excl;  // reuse as cursor
    __syncthreads();
    for (int p = lo + t; p < hi; p += 128) {
        unsigned pk = ebuf[p];
        int pos = atomicAdd(&deg[pk >> 16], 1);
        csr_src[pos] = (int)(pk & 0xFFFFu);
    }
}

// ---------------------------------------------------------------- GEMM: Y(fp16) = A @ W, 1-term fp16 MFMA
// W single fp16 plane in LDS (34.8 KB -> 4 blocks/CU). B-tile n0 covers
// W-cols {lm*8+n0}; rotated layout keeps LDS banks at 2 lanes/bank (free).
// Epilogue: 8 RNE halves packed into one 16 B store per (t,rg).
template <bool AF32>
__global__ __launch_bounds__(256) void gemm_mfma(const float* __restrict__ Xf,
                                                 const __half* __restrict__ Xh,
                                                 const short* __restrict__ Wsp,
                                                 __half* __restrict__ Y, int nrows) {
    __shared__ short Wp[PSTR];  // 34.8 KB
    int tid = threadIdx.x;
    {
        const short8* g = (const short8*)Wsp;  // 2176 short8
        #pragma unroll
        for (int i = 0; i < 9; ++i) {
            int e = tid + 256 * i;
            if (e < PSTR / 8) *(short8*)&Wp[e * 8] = g[e];
        }
    }
    int wave = tid >> 6;
    int lane = tid & 63;
    int lm = lane & 15;   // A row within tile / B tile-col / D col
    int lq = lane >> 4;   // k-octet selector / D row-quad
    int row_t0 = blockIdx.x * 128 + wave * 32;  // this wave: rows [row_t0, row_t0+32)

    float4v acc[2][8];
    #pragma unroll
    for (int t = 0; t < 2; ++t)
        #pragma unroll
        for (int i = 0; i < 8; ++i) acc[t][i] = (float4v){0.f, 0.f, 0.f, 0.f};

    __syncthreads();
    #pragma unroll
    for (int kk = 0; kk < 4; ++kk) {
        half8 a[2];
        #pragma unroll
        for (int t = 0; t < 2; ++t) {
            int r = min(row_t0 + t * 16 + lm, nrows - 1);
            size_t ao = (size_t)r * DIM + kk * 32 + lq * 8;
            if (AF32) {
                float4 xa = *(const float4*)(Xf + ao);
                float4 xb = *(const float4*)(Xf + ao + 4);
                a[t][0] = (_Float16)xa.x; a[t][1] = (_Float16)xa.y;
                a[t][2] = (_Float16)xa.z; a[t][3] = (_Float16)xa.w;
                a[t][4] = (_Float16)xb.x; a[t][5] = (_Float16)xb.y;
                a[t][6] = (_Float16)xb.z; a[t][7] = (_Float16)xb.w;
            } else {
                S8H8 u;
                u.s = *(const short8*)((const short*)Xh + ao);
                a[t] = u.h;
            }
        }
        int pk = (kk * 32 + lq * 8 + 8 * lm) & 127;  // rotated k offset for row 8lm+n0
        #pragma unroll
        for (int n0 = 0; n0 < 8; ++n0) {
            S8H8 b;
            b.s = *(const short8*)&Wp[(lm * 8 + n0) * WPAD + pk];
            #pragma unroll
            for (int t = 0; t < 2; ++t)
                acc[t][n0] = __builtin_amdgcn_mfma_f32_16x16x32_f16(a[t], b.h, acc[t][n0], 0, 0, 0);
        }
    }
    // D: tile-col lm -> W-col lm*8+n0; lane's 8 n0 are contiguous cols lm*8..+7.
    #pragma unroll
    for (int t = 0; t < 2; ++t)
        #pragma unroll
        for (int rg = 0; rg < 4; ++rg) {
            int row = row_t0 + t * 16 + lq * 4 + rg;
            if (row < nrows) {
                short8 o;
                #pragma unroll
                for (int j = 0; j < 8; ++j) {
                    SH c;
                    c.h = (_Float16)acc[t][j][rg];  // RNE
                    o[j] = c.s;
                }
                *(short8*)((short*)Y + (size_t)row * DIM + lm * 8) = o;
            }
        }
}

// ---------------------------------------------------------------- aggregation: 8 groups x 16 lanes x 16 B
// One node per 128-thread block; a 64-lane wave fetches 4 full 256 B rows
// = 16 L2 lines per instruction. Output fp16 (next GEMM A / pool in).
template <bool RELU>
__global__ __launch_bounds__(128) void agg_kernel(const __half* __restrict__ H,
                                                  __half* __restrict__ O16,
                                                  const int* __restrict__ rowoff,
                                                  const int* __restrict__ csr_src,
                                                  const float* __restrict__ dinv) {
    __shared__ float part[8][DIM];
    int i = blockIdx.x;
    int tid = threadIdx.x;
    int grp = tid >> 4;   // 0..7 edge-group
    int ln = tid & 15;    // lane in group; owns cols ln*8 .. ln*8+8
    int s = rowoff[i], e = rowoff[i + 1];
    const __half* Hc = H + ln * 8;

    float a[8] = {0.f, 0.f, 0.f, 0.f, 0.f, 0.f, 0.f, 0.f};
    int p = s + grp;
    for (; p + 8 < e; p += 16) {
        int u0 = csr_src[p];
        int u1 = csr_src[p + 8];
        float d0 = dinv[u0], d1 = dinv[u1];
        short8 q0 = *(const short8*)(Hc + (size_t)u0 * DIM);
        short8 q1 = *(const short8*)(Hc + (size_t)u1 * DIM);
        #pragma unroll
        for (int k = 0; k < 8; ++k) {
            a[k] = fmaf(d0, __half2float(((const __half*)&q0)[k]), a[k]);
            a[k] = fmaf(d1, __half2float(((const __half*)&q1)[k]), a[k]);
        }
    }
    if (p < e) {
        int u = csr_src[p];
        float d = dinv[u];
        short8 q = *(const short8*)(Hc + (size_t)u * DIM);
        #pragma unroll
        for (int k = 0; k < 8; ++k)
            a[k] = fmaf(d, __half2float(((const __half*)&q)[k]), a[k]);
    }
    #pragma unroll
    for (int k = 0; k < 8; k += 4)
        *(float4*)&part[grp][ln * 8 + k] = make_float4(a[k], a[k + 1], a[k + 2], a[k + 3]);
    __syncthreads();
    // thread tid finalizes column tid
    int col = tid;
    float tot = 0.f;
    #pragma unroll
    for (int g2 = 0; g2 < 8; ++g2) tot += part[g2][col];
    float di = dinv[i];
    tot = fmaf(di, __half2float(H[(size_t)i * DIM + col]), tot);  // self-loop
    float v = di * tot;
    if (RELU) v = fmaxf(v, 0.0f);  // relu fused (reference: relu before next conv)
    O16[(size_t)i * DIM + col] = __float2half(v);
}

// ---------------------------------------------------------------- pooling stage 1: per-(graph,slice) partials (fp16 in)
// 512 blocks (NG x PSLICE) -> enough parallel row-streams to stay BW-bound.
union U4 { ushort4 u; __half h[4]; };
__global__ __launch_bounds__(128) void pool_part(const __half* __restrict__ H,
                                                 const int* __restrict__ first,
                                                 float* __restrict__ ppart) {
    __shared__ float part[4][DIM];
    int g = blockIdx.x;
    int sl = blockIdx.y;
    int tid = threadIdx.x;
    int rg = tid >> 5, ln = tid & 31;
    int s = first[g], e = first[g + 1];
    float a0 = 0.f, a1 = 0.f, a2 = 0.f, a3 = 0.f;
    for (int r = s + sl * 4 + rg; r < e; r += PSLICE * 4) {
        U4 w;
        w.u = *(const ushort4*)(H + (size_t)r * DIM + ln * 4);
        a0 += __half2float(w.h[0]);
        a1 += __half2float(w.h[1]);
        a2 += __half2float(w.h[2]);
        a3 += __half2float(w.h[3]);
    }
    *(float4*)&part[rg][ln * 4] = make_float4(a0, a1, a2, a3);
    __syncthreads();
    float tot = part[0][tid] + part[1][tid] + part[2][tid] + part[3][tid];
    ppart[(size_t)(g * PSLICE + sl) * DIM + tid] = tot;
}

// ---------------------------------------------------------------- pool reduce + MLP (fused)
__global__ __launch_bounds__(128) void mlp_kernel(const float* __restrict__ ppart,
                                                  const int* __restrict__ first,
                                                  const float* __restrict__ M0w,
                                                  const float* __restrict__ M0b,
                                                  const float* __restrict__ M1w,
                                                  const float* __restrict__ M1b,
                                                  float* __restrict__ out) {
    __shared__ float p[DIM];
    __shared__ float t[DIM];
    int g = blockIdx.x;
    int j = threadIdx.x;
    float tot = 0.f;
    #pragma unroll
    for (int sl = 0; sl < PSLICE; ++sl)
        tot += ppart[(size_t)(g * PSLICE + sl) * DIM + j];
    float cnt = (float)max(first[g + 1] - first[g], 1);
    p[j] = tot / cnt;
    __syncthreads();
    float acc = M0b[j];
    #pragma unroll 8
    for (int k = 0; k < DIM; ++k) acc = fmaf(p[k], M0w[k * DIM + j], acc);
    t[j] = fmaxf(acc, 0.0f);
    __syncthreads();
    if (j < NOUT) {
        float o = M1b[j];
        #pragma unroll 8
        for (int k = 0; k < DIM; ++k) o = fmaf(t[k], M1w[k * NOUT + j], o);
        out[g * NOUT + j] = o;
    }
}

// ---------------------------------------------------------------- launcher
extern "C" void kernel_launch(void* const* d_in, const int* in_sizes, int n_in,
                              void* d_out, int out_size, void* d_ws, size_t ws_size,
                              hipStream_t stream) {
    const float* x   = (const float*)d_in[0];
    const float* W0  = (const float*)d_in[1];
    const float* W1  = (const float*)d_in[2];
    const float* W2  = (const float*)d_in[3];
    const float* M0w = (const float*)d_in[4];
    const float* M0b = (const float*)d_in[5];
    const float* M1w = (const float*)d_in[6];
    const float* M1b = (const float*)d_in[7];
    const int* ei    = (const int*)d_in[8];
    const int* batch = (const int*)d_in[9];
    float* out = (float*)d_out;

    char* ws = (char*)d_ws;
    size_t off = 0;
    auto take = [&](size_t bytes) -> void* {
        void* p = ws + off;
        off = (off + bytes + 255) & ~(size_t)255;
        return p;
    };
    __half* hA   = (__half*)take((size_t)NN * DIM * 2);   // fp16 GEMM output (gathered)
    __half* hB   = (__half*)take((size_t)NN * DIM * 2);   // fp16 agg output (GEMM A / pool in)
    unsigned* ebuf = (unsigned*)take((size_t)NE * 4);
    int* csr_src = (int*)take((size_t)NE * 4);
    int* blkhist = (int*)take((size_t)HBLK * NBKT * 4);
    int* bintot  = (int*)take((size_t)NBKT * 4);
    int* bucket_base = (int*)take((size_t)(NBKT + 1) * 4);
    int* rowoff  = (int*)take((size_t)(NN + 1) * 4);
    float* dinv  = (float*)take((size_t)NN * 4);
    int* first   = (int*)take((size_t)(NG + 1) * 4);
    float* ppart = (float*)take((size_t)NG * PSLICE * DIM * 4);
    short* wsp   = (short*)take((size_t)3 * PSTR * 2);
    (void)ws_size; (void)in_sizes; (void)n_in; (void)out_size;

    // ---- fused prep (W fp16 + hist + bounds), then CSR build
    prep_kernel<<<PREP_NB, 256, 0, stream>>>(W0, W1, W2, wsp, ei, blkhist, batch, first);
    scan_all<<<NBKT, 256, 0, stream>>>(blkhist, bintot);
    base_scan_kernel<<<1, 512, 0, stream>>>(bintot, bucket_base);
    bucket_scatter<<<HBLK, 256, 0, stream>>>(ei, blkhist, bucket_base, ebuf);
    build_csr<<<NBKT, 128, 0, stream>>>(ebuf, bucket_base, rowoff, csr_src, dinv);

    // ---- 3x (GEMM -> aggregate); everything fp16 between stages
    const int GB = (NN + 127) / 128;  // 391 gemm blocks
    gemm_mfma<true><<<GB, 256, 0, stream>>>(x, nullptr, wsp, hA, NN);
    agg_kernel<true><<<NN, 128, 0, stream>>>(hA, hB, rowoff, csr_src, dinv);
    gemm_mfma<false><<<GB, 256, 0, stream>>>(nullptr, hB, wsp + PSTR, hA, NN);
    agg_kernel<true><<<NN, 128, 0, stream>>>(hA, hB, rowoff, csr_src, dinv);
    gemm_mfma<false><<<GB, 256, 0, stream>>>(nullptr, hB, wsp + 2 * PSTR, hA, NN);
    agg_kernel<false><<<NN, 128, 0, stream>>>(hA, hB, rowoff, csr_src, dinv);

    // ---- pool + MLP (two-stage: 512-block partials, then 64-block reduce+MLP)
    dim3 pgrid(NG, PSLICE);
    pool_part<<<pgrid, 128, 0, stream>>>(hB, first, ppart);
    mlp_kernel<<<NG, 128, 0, stream>>>(ppart, first, M0w, M0b, M1w, M1b, out);
}

// Round 16
// 268.584 us; speedup vs baseline: 1.0727x; 1.0148x over previous
//
#include <hip/hip_runtime.h>
#include <hip/hip_fp16.h>

#define NN 50000      // nodes
#define NE 800000     // edges
#define DIM 128       // feature dim (D == H)
#define NG 64         // graphs
#define NOUT 10       // output dim

#define NBKT 391      // coarse buckets: ceil(NN/128), dst>>7
#define HBLK 256      // histogram/scatter blocks
#define CHUNK ((NE + HBLK - 1) / HBLK)   // 3125 edges per block
#define PSLICE 8      // pooling slices per graph

#define WPAD 136                 // W LDS/global row stride in shorts (16B-aligned rows)
#define PSTR (DIM * WPAD)        // one W plane = 17408 shorts (34.8 KB)

typedef __attribute__((ext_vector_type(8))) short short8;
typedef __attribute__((ext_vector_type(8))) _Float16 half8;
typedef __attribute__((ext_vector_type(4))) float float4v;

union S8H8 { short8 s; half8 h; };
union SH { short s; _Float16 h; };

// ---------------------------------------------------------------- fused prep:
// blocks [0,48)      : W f32 [k][n] -> fp16 RNE, transposed [n][k],
//                      row-rotated (phys_k = (k + 8*(n>>3)) & 127), stride WPAD
// blocks [48,304)    : per-block dst-bucket histogram
// block  304         : graph boundaries (batch sorted)
#define PREP_WB 48
#define PREP_HB (PREP_WB + HBLK)   // 304
#define PREP_NB (PREP_HB + 1)      // 305
__global__ __launch_bounds__(256) void prep_kernel(const float* __restrict__ W0,
                                                   const float* __restrict__ W1,
                                                   const float* __restrict__ W2,
                                                   short* __restrict__ wsp,
                                                   const int* __restrict__ ei,
                                                   int* __restrict__ blkhist,
                                                   const int* __restrict__ batch,
                                                   int* __restrict__ first) {
    __shared__ int h[NBKT];
    int bx = blockIdx.x;
    if (bx < PREP_WB) {
        int w = bx >> 4;
        int sub = bx & 15;
        const float* W = (w == 0) ? W0 : (w == 1) ? W1 : W2;
        short* Wp = wsp + w * PSTR;
        #pragma unroll
        for (int t = 0; t < 4; ++t) {
            int idx = sub * 1024 + t * 256 + threadIdx.x;
            int k = idx >> 7, n = idx & 127;
            int phys = n * WPAD + ((k + 8 * (n >> 3)) & 127);
            SH c;
            c.h = (_Float16)W[idx];  // RNE
            Wp[phys] = c.s;
        }
    } else if (bx < PREP_HB) {
        int b = bx - PREP_WB;
        for (int i = threadIdx.x; i < NBKT; i += 256) h[i] = 0;
        __syncthreads();
        int lo = b * CHUNK, hi = min(lo + CHUNK, NE);
        for (int e = lo + threadIdx.x; e < hi; e += 256)
            atomicAdd(&h[ei[NE + e] >> 7], 1);  // LDS atomic
        __syncthreads();
        for (int i = threadIdx.x; i < NBKT; i += 256)
            blkhist[b * NBKT + i] = h[i];
    } else {
        int g = threadIdx.x;
        if (g <= NG) {
            int lo = 0, hi = NN;
            while (lo < hi) {
                int mid = (lo + hi) >> 1;
                if (batch[mid] < g) lo = mid + 1; else hi = mid;
            }
            first[g] = lo;  // lower_bound(batch, g)
        }
    }
}

// ---------------------------------------------------------------- scan_all: per-bucket column scan + totals
__global__ __launch_bounds__(256) void scan_all(int* __restrict__ blkhist,
                                                int* __restrict__ bintot) {
    __shared__ int s[256];
    int bin = blockIdx.x;
    int t = threadIdx.x;
    int v = blkhist[t * NBKT + bin];
    s[t] = v;
    __syncthreads();
    #pragma unroll
    for (int off = 1; off < 256; off <<= 1) {
        int tv = (t >= off) ? s[t - off] : 0;
        __syncthreads();
        s[t] += tv;
        __syncthreads();
    }
    blkhist[t * NBKT + bin] = s[t] - v;  // exclusive (bucket-local)
    if (t == 255) bintot[bin] = s[255];
}

// -------- local 512-wide exclusive scan of bintot -> base[] (LDS), 256 threads
// pairs-then-scan: thread t owns elements 2t, 2t+1.
__device__ __forceinline__ void local_base_scan(const int* __restrict__ bintot,
                                                int* a /*[512]*/, int* ps /*[256]*/,
                                                int* base /*[512]*/) {
    int t = threadIdx.x & 255;
    a[2 * t]     = (2 * t < NBKT)     ? bintot[2 * t]     : 0;
    a[2 * t + 1] = (2 * t + 1 < NBKT) ? bintot[2 * t + 1] : 0;
    __syncthreads();
    int loc = a[2 * t] + a[2 * t + 1];
    ps[t] = loc;
    __syncthreads();
    #pragma unroll
    for (int off = 1; off < 256; off <<= 1) {
        int tv = (t >= off) ? ps[t - off] : 0;
        __syncthreads();
        ps[t] += tv;
        __syncthreads();
    }
    int excl = ps[t] - loc;
    base[2 * t] = excl;
    base[2 * t + 1] = excl + a[2 * t];
    __syncthreads();
}

// ---------------------------------------------------------------- scatter edges into buckets (packed)
__global__ __launch_bounds__(256) void bucket_scatter(const int* __restrict__ ei,
                                                      const int* __restrict__ blkhist,
                                                      const int* __restrict__ bintot,
                                                      unsigned* __restrict__ ebuf) {
    __shared__ int a[512];
    __shared__ int ps[256];
    __shared__ int base[512];
    __shared__ int cur[NBKT];
    int b = blockIdx.x;
    local_base_scan(bintot, a, ps, base);
    for (int i = threadIdx.x; i < NBKT; i += 256)
        cur[i] = blkhist[b * NBKT + i] + base[i];
    __syncthreads();
    int lo = b * CHUNK, hi = min(lo + CHUNK, NE);
    for (int e = lo + threadIdx.x; e < hi; e += 256) {
        int s = ei[e];
        int d = ei[NE + e];
        int pos = atomicAdd(&cur[d >> 7], 1);  // LDS atomic; block owns disjoint ranges
        ebuf[pos] = ((unsigned)(d & 127) << 16) | (unsigned)s;  // src < 2^16
    }
}

// ---------------------------------------------------------------- per-bucket CSR build (256 thr; scans use first 128)
__global__ __launch_bounds__(256) void build_csr(const unsigned* __restrict__ ebuf,
                                                 const int* __restrict__ bintot,
                                                 int* __restrict__ rowoff,
                                                 int* __restrict__ csr_src,
                                                 float* __restrict__ dinv) {
    __shared__ int a[512];
    __shared__ int ps[256];
    __shared__ int base[512];
    __shared__ int deg[128];
    __shared__ int loff[128];
    int g = blockIdx.x;
    int t = threadIdx.x;
    local_base_scan(bintot, a, ps, base);
    int lo = base[g];
    int hi = (g + 1 < NBKT) ? base[g + 1] : NE;
    if (t < 128) deg[t] = 0;
    __syncthreads();
    for (int p = lo + t; p < hi; p += 256)
        atomicAdd(&deg[ebuf[p] >> 16], 1);
    __syncthreads();
    int v = (t < 128) ? deg[t] : 0;
    if (t < 128) loff[t] = v;
    __syncthreads();
    #pragma unroll
    for (int off = 1; off < 128; off <<= 1) {
        int tv = (t < 128 && t >= off) ? loff[t - off] : 0;
        __syncthreads();
        if (t < 128) loff[t] += tv;
        __syncthreads();
    }
    if (t < 128) {
        int excl = loff[t] - v;
        int node = g * 128 + t;
        if (node < NN) {
            rowoff[node] = lo + excl;
            dinv[node] = 1.0f / sqrtf((float)v + 1.0f);
        }
        if (node == 0) rowoff[NN] = NE;
        deg[t] = lo + excl;  // reuse as cursor
    }
    __syncthreads();
    for (int p = lo + t; p < hi; p += 256) {
        unsigned pk = ebuf[p];
        int pos = atomicAdd(&deg[pk >> 16], 1);
        csr_src[pos] = (int)(pk & 0xFFFFu);
    }
}

// ---------------------------------------------------------------- GEMM: Y(fp16) = A @ W, 1-term fp16 MFMA
// 64-row x 128-thread blocks -> 782 blocks (3.05/CU, near-even makespan;
// 4 co-resident at 34.8 KB LDS). B-tile n0 covers W-cols {lm*8+n0};
// rotated layout keeps LDS banks at 2 lanes/bank (free).
template <bool AF32>
__global__ __launch_bounds__(128) void gemm_mfma(const float* __restrict__ Xf,
                                                 const __half* __restrict__ Xh,
                                                 const short* __restrict__ Wsp,
                                                 __half* __restrict__ Y, int nrows) {
    __shared__ short Wp[PSTR];  // 34.8 KB
    int tid = threadIdx.x;
    {
        const short8* g = (const short8*)Wsp;  // 2176 short8
        #pragma unroll
        for (int i = 0; i < 17; ++i) {
            int e = tid + 128 * i;  // 128*17 = 2176 exactly
            *(short8*)&Wp[e * 8] = g[e];
        }
    }
    int wave = tid >> 6;  // 0..1
    int lane = tid & 63;
    int lm = lane & 15;   // A row within tile / B tile-col / D col
    int lq = lane >> 4;   // k-octet selector / D row-quad
    int row_t0 = blockIdx.x * 64 + wave * 32;  // this wave: rows [row_t0, row_t0+32)

    float4v acc[2][8];
    #pragma unroll
    for (int t = 0; t < 2; ++t)
        #pragma unroll
        for (int i = 0; i < 8; ++i) acc[t][i] = (float4v){0.f, 0.f, 0.f, 0.f};

    __syncthreads();
    #pragma unroll
    for (int kk = 0; kk < 4; ++kk) {
        half8 a[2];
        #pragma unroll
        for (int t = 0; t < 2; ++t) {
            int r = min(row_t0 + t * 16 + lm, nrows - 1);
            size_t ao = (size_t)r * DIM + kk * 32 + lq * 8;
            if (AF32) {
                float4 xa = *(const float4*)(Xf + ao);
                float4 xb = *(const float4*)(Xf + ao + 4);
                a[t][0] = (_Float16)xa.x; a[t][1] = (_Float16)xa.y;
                a[t][2] = (_Float16)xa.z; a[t][3] = (_Float16)xa.w;
                a[t][4] = (_Float16)xb.x; a[t][5] = (_Float16)xb.y;
                a[t][6] = (_Float16)xb.z; a[t][7] = (_Float16)xb.w;
            } else {
                S8H8 u;
                u.s = *(const short8*)((const short*)Xh + ao);
                a[t] = u.h;
            }
        }
        int pk = (kk * 32 + lq * 8 + 8 * lm) & 127;  // rotated k offset for row 8lm+n0
        #pragma unroll
        for (int n0 = 0; n0 < 8; ++n0) {
            S8H8 b;
            b.s = *(const short8*)&Wp[(lm * 8 + n0) * WPAD + pk];
            #pragma unroll
            for (int t = 0; t < 2; ++t)
                acc[t][n0] = __builtin_amdgcn_mfma_f32_16x16x32_f16(a[t], b.h, acc[t][n0], 0, 0, 0);
        }
    }
    // D: tile-col lm -> W-col lm*8+n0; lane's 8 n0 are contiguous cols lm*8..+7.
    #pragma unroll
    for (int t = 0; t < 2; ++t)
        #pragma unroll
        for (int rg = 0; rg < 4; ++rg) {
            int row = row_t0 + t * 16 + lq * 4 + rg;
            if (row < nrows) {
                short8 o;
                #pragma unroll
                for (int j = 0; j < 8; ++j) {
                    SH c;
                    c.h = (_Float16)acc[t][j][rg];  // RNE
                    o[j] = c.s;
                }
                *(short8*)((short*)Y + (size_t)row * DIM + lm * 8) = o;
            }
        }
}

// ---------------------------------------------------------------- aggregation: 8 groups x 16 lanes x 16 B
// One node per 128-thread block; a 64-lane wave fetches 4 full 256 B rows
// = 16 L2 lines per instruction. Output fp16 (next GEMM A / pool in).
template <bool RELU>
__global__ __launch_bounds__(128) void agg_kernel(const __half* __restrict__ H,
                                                  __half* __restrict__ O16,
                                                  const int* __restrict__ rowoff,
                                                  const int* __restrict__ csr_src,
                                                  const float* __restrict__ dinv) {
    __shared__ float part[8][DIM];
    int i = blockIdx.x;
    int tid = threadIdx.x;
    int grp = tid >> 4;   // 0..7 edge-group
    int ln = tid & 15;    // lane in group; owns cols ln*8 .. ln*8+8
    int s = rowoff[i], e = rowoff[i + 1];
    const __half* Hc = H + ln * 8;

    float a[8] = {0.f, 0.f, 0.f, 0.f, 0.f, 0.f, 0.f, 0.f};
    int p = s + grp;
    for (; p + 8 < e; p += 16) {
        int u0 = csr_src[p];
        int u1 = csr_src[p + 8];
        float d0 = dinv[u0], d1 = dinv[u1];
        short8 q0 = *(const short8*)(Hc + (size_t)u0 * DIM);
        short8 q1 = *(const short8*)(Hc + (size_t)u1 * DIM);
        #pragma unroll
        for (int k = 0; k < 8; ++k) {
            a[k] = fmaf(d0, __half2float(((const __half*)&q0)[k]), a[k]);
            a[k] = fmaf(d1, __half2float(((const __half*)&q1)[k]), a[k]);
        }
    }
    if (p < e) {
        int u = csr_src[p];
        float d = dinv[u];
        short8 q = *(const short8*)(Hc + (size_t)u * DIM);
        #pragma unroll
        for (int k = 0; k < 8; ++k)
            a[k] = fmaf(d, __half2float(((const __half*)&q)[k]), a[k]);
    }
    #pragma unroll
    for (int k = 0; k < 8; k += 4)
        *(float4*)&part[grp][ln * 8 + k] = make_float4(a[k], a[k + 1], a[k + 2], a[k + 3]);
    __syncthreads();
    // thread tid finalizes column tid
    int col = tid;
    float tot = 0.f;
    #pragma unroll
    for (int g2 = 0; g2 < 8; ++g2) tot += part[g2][col];
    float di = dinv[i];
    tot = fmaf(di, __half2float(H[(size_t)i * DIM + col]), tot);  // self-loop
    float v = di * tot;
    if (RELU) v = fmaxf(v, 0.0f);  // relu fused (reference: relu before next conv)
    O16[(size_t)i * DIM + col] = __float2half(v);
}

// ---------------------------------------------------------------- pooling stage 1: per-(graph,slice) partials (fp16 in)
// 512 blocks (NG x PSLICE) -> enough parallel row-streams to stay BW-bound.
union U4 { ushort4 u; __half h[4]; };
__global__ __launch_bounds__(128) void pool_part(const __half* __restrict__ H,
                                                 const int* __restrict__ first,
                                                 float* __restrict__ ppart) {
    __shared__ float part[4][DIM];
    int g = blockIdx.x;
    int sl = blockIdx.y;
    int tid = threadIdx.x;
    int rg = tid >> 5, ln = tid & 31;
    int s = first[g], e = first[g + 1];
    float a0 = 0.f, a1 = 0.f, a2 = 0.f, a3 = 0.f;
    for (int r = s + sl * 4 + rg; r < e; r += PSLICE * 4) {
        U4 w;
        w.u = *(const ushort4*)(H + (size_t)r * DIM + ln * 4);
        a0 += __half2float(w.h[0]);
        a1 += __half2float(w.h[1]);
        a2 += __half2float(w.h[2]);
        a3 += __half2float(w.h[3]);
    }
    *(float4*)&part[rg][ln * 4] = make_float4(a0, a1, a2, a3);
    __syncthreads();
    float tot = part[0][tid] + part[1][tid] + part[2][tid] + part[3][tid];
    ppart[(size_t)(g * PSLICE + sl) * DIM + tid] = tot;
}

// ---------------------------------------------------------------- pool reduce + MLP (fused)
__global__ __launch_bounds__(128) void mlp_kernel(const float* __restrict__ ppart,
                                                  const int* __restrict__ first,
                                                  const float* __restrict__ M0w,
                                                  const float* __restrict__ M0b,
                                                  const float* __restrict__ M1w,
                                                  const float* __restrict__ M1b,
                                                  float* __restrict__ out) {
    __shared__ float p[DIM];
    __shared__ float t[DIM];
    int g = blockIdx.x;
    int j = threadIdx.x;
    float tot = 0.f;
    #pragma unroll
    for (int sl = 0; sl < PSLICE; ++sl)
        tot += ppart[(size_t)(g * PSLICE + sl) * DIM + j];
    float cnt = (float)max(first[g + 1] - first[g], 1);
    p[j] = tot / cnt;
    __syncthreads();
    float acc = M0b[j];
    #pragma unroll 8
    for (int k = 0; k < DIM; ++k) acc = fmaf(p[k], M0w[k * DIM + j], acc);
    t[j] = fmaxf(acc, 0.0f);
    __syncthreads();
    if (j < NOUT) {
        float o = M1b[j];
        #pragma unroll 8
        for (int k = 0; k < DIM; ++k) o = fmaf(t[k], M1w[k * NOUT + j], o);
        out[g * NOUT + j] = o;
    }
}

// ---------------------------------------------------------------- launcher
extern "C" void kernel_launch(void* const* d_in, const int* in_sizes, int n_in,
                              void* d_out, int out_size, void* d_ws, size_t ws_size,
                              hipStream_t stream) {
    const float* x   = (const float*)d_in[0];
    const float* W0  = (const float*)d_in[1];
    const float* W1  = (const float*)d_in[2];
    const float* W2  = (const float*)d_in[3];
    const float* M0w = (const float*)d_in[4];
    const float* M0b = (const float*)d_in[5];
    const float* M1w = (const float*)d_in[6];
    const float* M1b = (const float*)d_in[7];
    const int* ei    = (const int*)d_in[8];
    const int* batch = (const int*)d_in[9];
    float* out = (float*)d_out;

    char* ws = (char*)d_ws;
    size_t off = 0;
    auto take = [&](size_t bytes) -> void* {
        void* p = ws + off;
        off = (off + bytes + 255) & ~(size_t)255;
        return p;
    };
    __half* hA   = (__half*)take((size_t)NN * DIM * 2);   // fp16 GEMM output (gathered)
    __half* hB   = (__half*)take((size_t)NN * DIM * 2);   // fp16 agg output (GEMM A / pool in)
    unsigned* ebuf = (unsigned*)take((size_t)NE * 4);
    int* csr_src = (int*)take((size_t)NE * 4);
    int* blkhist = (int*)take((size_t)HBLK * NBKT * 4);
    int* bintot  = (int*)take((size_t)NBKT * 4);
    int* rowoff  = (int*)take((size_t)(NN + 1) * 4);
    float* dinv  = (float*)take((size_t)NN * 4);
    int* first   = (int*)take((size_t)(NG + 1) * 4);
    float* ppart = (float*)take((size_t)NG * PSLICE * DIM * 4);
    short* wsp   = (short*)take((size_t)3 * PSTR * 2);
    (void)ws_size; (void)in_sizes; (void)n_in; (void)out_size;

    // ---- fused prep (W fp16 + hist + bounds), then CSR build (base scanned locally)
    prep_kernel<<<PREP_NB, 256, 0, stream>>>(W0, W1, W2, wsp, ei, blkhist, batch, first);
    scan_all<<<NBKT, 256, 0, stream>>>(blkhist, bintot);
    bucket_scatter<<<HBLK, 256, 0, stream>>>(ei, blkhist, bintot, ebuf);
    build_csr<<<NBKT, 256, 0, stream>>>(ebuf, bintot, rowoff, csr_src, dinv);

    // ---- 3x (GEMM -> aggregate); everything fp16 between stages
    const int GB = (NN + 63) / 64;  // 782 gemm blocks (64 rows x 128 thr)
    gemm_mfma<true><<<GB, 128, 0, stream>>>(x, nullptr, wsp, hA, NN);
    agg_kernel<true><<<NN, 128, 0, stream>>>(hA, hB, rowoff, csr_src, dinv);
    gemm_mfma<false><<<GB, 128, 0, stream>>>(nullptr, hB, wsp + PSTR, hA, NN);
    agg_kernel<true><<<NN, 128, 0, stream>>>(hA, hB, rowoff, csr_src, dinv);
    gemm_mfma<false><<<GB, 128, 0, stream>>>(nullptr, hB, wsp + 2 * PSTR, hA, NN);
    agg_kernel<false><<<NN, 128, 0, stream>>>(hA, hB, rowoff, csr_src, dinv);

    // ---- pool + MLP (two-stage: 512-block partials, then 64-block reduce+MLP)
    dim3 pgrid(NG, PSLICE);
    pool_part<<<pgrid, 128, 0, stream>>>(hB, first, ppart);
    mlp_kernel<<<NG, 128, 0, stream>>>(ppart, first, M0w, M0b, M1w, M1b, out);
}